// Round 1
// baseline (122.396 us; speedup 1.0000x reference)
//
#include <hip/hip_runtime.h>

typedef __attribute__((ext_vector_type(8))) short bf16x8;
typedef __attribute__((ext_vector_type(4))) float f32x4;

#define TOK 16384
#define DIM 128
#define SEQ 2048

__device__ inline unsigned short f2bf(float f){
  union { float f; unsigned int u; } v; v.f = f;
  unsigned int r = v.u + 0x7fffu + ((v.u >> 16) & 1u);
  return (unsigned short)(r >> 16);
}

__device__ inline void gld16(const void* g, const void* l){
  __builtin_amdgcn_global_load_lds((const __attribute__((address_space(1))) void*)g,
                                   (__attribute__((address_space(3))) void*)l, 16, 0, 0);
}

// ---------------- kernel 0: weights -> bf16, transposed [out][in], chunk-swizzled ----------------
__global__ __launch_bounds__(256) void prep_w(const float* __restrict__ W1, const float* __restrict__ Wq,
                                              const float* __restrict__ Wk, const float* __restrict__ Wv,
                                              unsigned short* __restrict__ wt){
  int w = blockIdx.x >> 2, qtr = blockIdx.x & 3;
  const float* W = (w==0)?W1:((w==1)?Wq:((w==2)?Wk:Wv));
  unsigned short* dst = wt + w*16384;
  int c = threadIdx.x & 127;
  int khalf = threadIdx.x >> 7;
  int kbase = qtr*32 + khalf*16;
  unsigned short tmp[16];
  #pragma unroll
  for (int i=0;i<16;i++) tmp[i] = f2bf(W[(kbase+i)*128 + c]);
  #pragma unroll
  for (int h=0;h<2;h++){
    int k0 = kbase + h*8;
    int chunk = (k0 >> 3) ^ (c & 7);
    bf16x8 pk;
    #pragma unroll
    for (int j=0;j<8;j++) pk[j] = (short)tmp[h*8+j];
    *reinterpret_cast<bf16x8*>(dst + c*128 + chunk*8) = pk;
  }
}

// ---------------- kernel 1: res = q@W1 ; qh/kh/vh = res@{Wq,Wk,Wv} ----------------
__global__ __launch_bounds__(256,1) void proj(const float* __restrict__ q, const unsigned short* __restrict__ wt,
                                              float* __restrict__ out,
                                              unsigned short* __restrict__ qh, unsigned short* __restrict__ khsw,
                                              unsigned short* __restrict__ vht){
  __shared__ unsigned short sW[4*128*128];   // 128 KB, [w][c][k chunk-swizzled]
  __shared__ unsigned short sX[64*128];      // 16 KB, rows chunk-swizzled (q, then res)
  unsigned short* sVh = sW;                  // alias: reuse W1 region after GEMM1 (8320 < 16384 ushorts)

  int tid = threadIdx.x;
  int lane = tid & 63, wid = tid >> 6;
  int l15 = lane & 15, lg = lane >> 4;
  int rowbase = blockIdx.x * 64;

  // stage all 4 weights (linear copy, ws already laid out + swizzled)
  #pragma unroll
  for (int p=0;p<32;p++)
    gld16((const char*)wt + p*4096 + tid*16, (const char*)sW + p*4096 + wid*1024);

  // stage q tile: f32 -> bf16, chunk-swizzled rows
  {
    int r = tid >> 2, cg = tid & 3;
    const float* qp = q + (size_t)(rowbase + r)*128 + cg*32;
    #pragma unroll
    for (int c8=0;c8<4;c8++){
      bf16x8 pk;
      #pragma unroll
      for (int j=0;j<8;j++) pk[j] = (short)f2bf(qp[c8*8 + j]);
      int chunk = (cg*4 + c8) ^ (r & 7);
      *reinterpret_cast<bf16x8*>(sX + r*128 + chunk*8) = pk;
    }
  }
  __syncthreads();

  auto gemm = [&](const unsigned short* sA, const unsigned short* sB, f32x4 acc[8]){
    #pragma unroll
    for (int ct=0;ct<8;ct++) acc[ct] = (f32x4){0.f,0.f,0.f,0.f};
    #pragma unroll
    for (int kt=0;kt<4;kt++){
      int ar = wid*16 + l15;
      bf16x8 a = *reinterpret_cast<const bf16x8*>(sA + ar*128 + (((kt*4+lg) ^ (ar&7))*8));
      #pragma unroll
      for (int ct=0;ct<8;ct++){
        int cc = ct*16 + l15;
        bf16x8 bb = *reinterpret_cast<const bf16x8*>(sB + cc*128 + (((kt*4+lg) ^ (cc&7))*8));
        acc[ct] = __builtin_amdgcn_mfma_f32_16x16x32_bf16(a, bb, acc[ct], 0, 0, 0);
      }
    }
  };

  f32x4 acc[8];

  // GEMM1: res
  gemm(sX, sW, acc);
  #pragma unroll
  for (int ct=0;ct<8;ct++)
    #pragma unroll
    for (int i=0;i<4;i++){
      int r = wid*16 + lg*4 + i, c = ct*16 + l15;
      int rg = rowbase + r;
      float v = acc[ct][i];
      out[rg*256 + 128 + c] = v;          // o[:,128:256] = res
      out[TOK*256 + rg*128 + c] = v;      // second output = res
    }
  __syncthreads();   // done reading q from sX and W1 from sW[0]
  #pragma unroll
  for (int ct=0;ct<8;ct++)
    #pragma unroll
    for (int i=0;i<4;i++){
      int r = wid*16 + lg*4 + i, c = ct*16 + l15;
      sX[r*128 + (((c>>3) ^ (r&7))*8) + (c&7)] = f2bf(acc[ct][i]);
    }
  __syncthreads();

  // GEMM2: qh (fold 1/sqrt(128))
  gemm(sX, sW + 16384, acc);
  const float invT = 0.088388347648318447f;
  #pragma unroll
  for (int ct=0;ct<8;ct++)
    #pragma unroll
    for (int i=0;i<4;i++){
      int r = wid*16 + lg*4 + i, c = ct*16 + l15;
      qh[(rowbase + r)*128 + c] = f2bf(acc[ct][i]*invT);
    }

  // GEMM3: kh, row-chunk-swizzled for conflict-free ds_read_b128 later
  gemm(sX, sW + 2*16384, acc);
  #pragma unroll
  for (int ct=0;ct<8;ct++)
    #pragma unroll
    for (int i=0;i<4;i++){
      int r = wid*16 + lg*4 + i, c = ct*16 + l15;
      int rg = rowbase + r;
      khsw[rg*128 + (c ^ ((rg&7)<<3))] = f2bf(acc[ct][i]);
    }

  // GEMM4: vh -> LDS -> transposed (per-batch [feat][n], 4-chunk swizzle) global write
  gemm(sX, sW + 3*16384, acc);
  #pragma unroll
  for (int ct=0;ct<8;ct++)
    #pragma unroll
    for (int i=0;i<4;i++){
      int r = wid*16 + lg*4 + i, c = ct*16 + l15;
      sVh[r*130 + c] = f2bf(acc[ct][i]);
    }
  __syncthreads();
  {
    int bb = rowbase >> 11;          // batch
    int n0 = rowbase & 2047;         // n offset in batch
    #pragma unroll
    for (int it=0; it<4; ++it){
      int idx = tid + it*256;        // 0..1023 = 128 feats x 8 chunks
      int f = idx >> 3, ch = idx & 7;
      bf16x8 pk;
      #pragma unroll
      for (int j=0;j<8;j++) pk[j] = (short)sVh[(ch*8+j)*130 + f];
      int ci  = (n0 >> 3) + ch;
      int cis = (ci & ~3) | ((ci ^ (f & 3)) & 3);
      *reinterpret_cast<bf16x8*>(vht + bb*(DIM*SEQ) + f*SEQ + cis*8) = pk;
    }
  }
}

// ---------------- kernel 2: flash attention with adj mask ----------------
__global__ __launch_bounds__(256,1) void attn(const unsigned short* __restrict__ qh,
                                              const unsigned short* __restrict__ khsw,
                                              const unsigned short* __restrict__ vht,
                                              const float* __restrict__ adj,
                                              float* __restrict__ out){
  __shared__ unsigned short sK[2][2][32*128];   // [dbuf][half][kv][feat]  (swizzled rows)
  __shared__ unsigned short sV[2][2][128*32];   // [dbuf][half][feat][kv]  (4-chunk swizzle)
  __shared__ float          sAdj[2][2][64*32];  // [dbuf][half][qrow][kv]
  __shared__ unsigned short sP[4][32*40];       // per-wave P, rows padded to 80B
  __shared__ float          sO[2][32*128];      // merge buffer
  __shared__ float          sML[2][2][32];

  int tid = threadIdx.x;
  int lane = tid & 63, wid = tid >> 6;
  int l15 = lane & 15, lg = lane >> 4;
  int rg = wid & 1, half = wid >> 1;
  int qbase = blockIdx.x * 64;
  int b = blockIdx.y;
  size_t adjb = (size_t)b * SEQ * SEQ;
  const unsigned short* vhb = vht + b * (DIM*SEQ);
  int tokbase = b*SEQ + qbase;

  // Q fragments: 2 row-subtiles x 4 k-tiles (qh already has 1/T folded)
  bf16x8 qf[2][4];
  #pragma unroll
  for (int mi=0;mi<2;mi++){
    const unsigned short* qp = qh + (size_t)(tokbase + rg*32 + mi*16 + l15)*128;
    #pragma unroll
    for (int kt=0;kt<4;kt++)
      qf[mi][kt] = *reinterpret_cast<const bf16x8*>(qp + kt*32 + lg*8);
  }

  f32x4 o[2][8];
  #pragma unroll
  for (int mi=0;mi<2;mi++)
    #pragma unroll
    for (int ct=0;ct<8;ct++) o[mi][ct] = (f32x4){0.f,0.f,0.f,0.f};
  float mrow[2][4], lrow[2][4];
  #pragma unroll
  for (int mi=0;mi<2;mi++)
    #pragma unroll
    for (int i=0;i<4;i++){ mrow[mi][i] = -3e38f; lrow[mi][i] = 0.f; }

  auto stage = [&](int tt, int db){
    #pragma unroll
    for (int h=0;h<2;h++){
      int kvb = h*1024 + tt*32;
      #pragma unroll
      for (int p=0;p<2;p++){
        { int row = (p*256 + tid) >> 4;
          gld16(khsw + (size_t)(b*SEQ + kvb + row)*128 + (tid & 15)*8,
                (const char*)sK[db][h] + p*4096 + wid*1024); }
        { int f = (p*256 + tid) >> 2;
          gld16(vhb + f*SEQ + kvb + (tid & 3)*8,
                (const char*)sV[db][h] + p*4096 + wid*1024); }
        { int row = (p*256 + tid) >> 3;
          gld16(adj + adjb + (size_t)(qbase + row)*SEQ + kvb + (tid & 7)*4,
                (const char*)sAdj[db][h] + p*4096 + wid*1024); }
      }
    }
  };

  stage(0, 0);
  __syncthreads();

  for (int t=0; t<32; ++t){
    int db = t & 1;
    if (t + 1 < 32) stage(t+1, db^1);

    const unsigned short* K = sK[db][half];
    const unsigned short* V = sV[db][half];
    const float* A = sAdj[db][half];

    // S = Q K^T  (scale already folded into qh)
    f32x4 s[2][2];
    #pragma unroll
    for (int mi=0;mi<2;mi++)
      #pragma unroll
      for (int ct=0;ct<2;ct++) s[mi][ct] = (f32x4){0.f,0.f,0.f,0.f};
    #pragma unroll
    for (int ct=0;ct<2;ct++)
      #pragma unroll
      for (int kt=0;kt<4;kt++){
        int kr = ct*16 + l15;
        bf16x8 kf = *reinterpret_cast<const bf16x8*>(K + kr*128 + (((kt*4+lg) ^ (kr&7))*8));
        s[0][ct] = __builtin_amdgcn_mfma_f32_16x16x32_bf16(qf[0][kt], kf, s[0][ct], 0,0,0);
        s[1][ct] = __builtin_amdgcn_mfma_f32_16x16x32_bf16(qf[1][kt], kf, s[1][ct], 0,0,0);
      }

    // mask
    #pragma unroll
    for (int mi=0;mi<2;mi++)
      #pragma unroll
      for (int i=0;i<4;i++){
        int r = rg*32 + mi*16 + lg*4 + i;
        float a0 = A[r*32 + l15];
        float a1 = A[r*32 + 16 + l15];
        if (a0 == 0.f) s[mi][0][i] = -1e9f;
        if (a1 == 0.f) s[mi][1][i] = -1e9f;
      }

    // online softmax (row stats replicated across each 16-lane group)
    float sc[2][4];
    #pragma unroll
    for (int mi=0;mi<2;mi++)
      #pragma unroll
      for (int i=0;i<4;i++){
        float tm = fmaxf(s[mi][0][i], s[mi][1][i]);
        tm = fmaxf(tm, __shfl_xor(tm, 1));
        tm = fmaxf(tm, __shfl_xor(tm, 2));
        tm = fmaxf(tm, __shfl_xor(tm, 4));
        tm = fmaxf(tm, __shfl_xor(tm, 8));
        float nm = fmaxf(mrow[mi][i], tm);
        float scv = __expf(mrow[mi][i] - nm);
        mrow[mi][i] = nm;
        float p0 = __expf(s[mi][0][i] - nm);
        float p1 = __expf(s[mi][1][i] - nm);
        s[mi][0][i] = p0; s[mi][1][i] = p1;
        float ps = p0 + p1;
        ps += __shfl_xor(ps, 1);
        ps += __shfl_xor(ps, 2);
        ps += __shfl_xor(ps, 4);
        ps += __shfl_xor(ps, 8);
        lrow[mi][i] = lrow[mi][i]*scv + ps;
        sc[mi][i] = scv;
      }
    #pragma unroll
    for (int mi=0;mi<2;mi++)
      #pragma unroll
      for (int ct=0;ct<8;ct++)
        #pragma unroll
        for (int i=0;i<4;i++)
          o[mi][ct][i] *= sc[mi][i];

    // P -> per-wave LDS (C-layout -> A-layout)
    unsigned short* Pw = sP[wid];
    #pragma unroll
    for (int mi=0;mi<2;mi++)
      #pragma unroll
      for (int ct=0;ct<2;ct++)
        #pragma unroll
        for (int i=0;i<4;i++){
          int r = mi*16 + lg*4 + i;
          Pw[r*40 + ct*16 + l15] = f2bf(s[mi][ct][i]);
        }
    bf16x8 pa[2];
    #pragma unroll
    for (int mi=0;mi<2;mi++)
      pa[mi] = *reinterpret_cast<const bf16x8*>(Pw + (mi*16 + l15)*40 + lg*8);

    // O += P V
    #pragma unroll
    for (int ct=0;ct<8;ct++){
      int f = ct*16 + l15;
      bf16x8 vf = *reinterpret_cast<const bf16x8*>(V + f*32 + ((lg ^ (f&3))*8));
      o[0][ct] = __builtin_amdgcn_mfma_f32_16x16x32_bf16(pa[0], vf, o[0][ct], 0,0,0);
      o[1][ct] = __builtin_amdgcn_mfma_f32_16x16x32_bf16(pa[1], vf, o[1][ct], 0,0,0);
    }
    __syncthreads();   // staged next tiles landed; everyone done with current buffers
  }

  // merge the two KV halves
  if (half == 1){
    #pragma unroll
    for (int mi=0;mi<2;mi++)
      #pragma unroll
      for (int ct=0;ct<8;ct++)
        #pragma unroll
        for (int i=0;i<4;i++){
          int r = mi*16 + lg*4 + i;
          sO[rg][r*128 + ct*16 + l15] = o[mi][ct][i];
        }
    if (l15 == 0){
      #pragma unroll
      for (int mi=0;mi<2;mi++)
        #pragma unroll
        for (int i=0;i<4;i++){
          int r = mi*16 + lg*4 + i;
          sML[rg][0][r] = mrow[mi][i];
          sML[rg][1][r] = lrow[mi][i];
        }
    }
  }
  __syncthreads();
  if (half == 0){
    float s0[2][4], s1[2][4];
    #pragma unroll
    for (int mi=0;mi<2;mi++)
      #pragma unroll
      for (int i=0;i<4;i++){
        int r = mi*16 + lg*4 + i;
        float m1 = sML[rg][0][r], l1 = sML[rg][1][r];
        float M = fmaxf(mrow[mi][i], m1);
        float a0 = __expf(mrow[mi][i] - M);
        float a1 = __expf(m1 - M);
        float L = lrow[mi][i]*a0 + l1*a1;
        float inv = 1.f / L;
        s0[mi][i] = a0*inv; s1[mi][i] = a1*inv;
      }
    #pragma unroll
    for (int mi=0;mi<2;mi++)
      #pragma unroll
      for (int ct=0;ct<8;ct++)
        #pragma unroll
        for (int i=0;i<4;i++){
          int r = mi*16 + lg*4 + i;
          float o1 = sO[rg][r*128 + ct*16 + l15];
          float val = o[mi][ct][i]*s0[mi][i] + o1*s1[mi][i];
          out[(size_t)(tokbase + rg*32 + r)*256 + ct*16 + l15] = val;
        }
  }
}

extern "C" void kernel_launch(void* const* d_in, const int* in_sizes, int n_in,
                              void* d_out, int out_size, void* d_ws, size_t ws_size,
                              hipStream_t stream){
  (void)in_sizes; (void)n_in; (void)out_size; (void)ws_size;
  const float* q   = (const float*)d_in[0];
  const float* adj = (const float*)d_in[3];
  const float* W1  = (const float*)d_in[4];
  const float* Wq  = (const float*)d_in[5];
  const float* Wk  = (const float*)d_in[6];
  const float* Wv  = (const float*)d_in[7];
  float* out = (float*)d_out;

  unsigned short* qh  = (unsigned short*)d_ws;   // 4 MB
  unsigned short* kh  = qh + TOK*DIM;            // 4 MB (pre-swizzled rows)
  unsigned short* vh  = kh + TOK*DIM;            // 4 MB (transposed per batch)
  unsigned short* wt  = vh + TOK*DIM;            // 128 KB

  prep_w<<<16, 256, 0, stream>>>(W1, Wq, Wk, Wv, wt);
  proj<<<256, 256, 0, stream>>>(q, wt, out, qh, kh, vh);
  attn<<<dim3(32, 8), 256, 0, stream>>>(qh, kh, vh, adj, out);
}

// Round 2
// 111.617 us; speedup vs baseline: 1.0966x; 1.0966x over previous
//
#include <hip/hip_runtime.h>

typedef __attribute__((ext_vector_type(8))) short bf16x8;
typedef __attribute__((ext_vector_type(4))) float f32x4;
typedef unsigned int u32;

#define TOK 16384
#define DIM 128
#define SEQ 2048

__device__ inline unsigned short f2bf(float f){
  union { float f; u32 u; } v; v.f = f;
  u32 r = v.u + 0x7fffu + ((v.u >> 16) & 1u);
  return (unsigned short)(r >> 16);
}

__device__ inline void gld16(const void* g, const void* l){
  __builtin_amdgcn_global_load_lds((const __attribute__((address_space(1))) void*)g,
                                   (__attribute__((address_space(3))) void*)l, 16, 0, 0);
}
__device__ inline void gld4(const void* g, const void* l){
  __builtin_amdgcn_global_load_lds((const __attribute__((address_space(1))) void*)g,
                                   (__attribute__((address_space(3))) void*)l, 4, 0, 0);
}

template<int CTRL>
__device__ inline float dppf(float x){
  return __builtin_bit_cast(float,
    __builtin_amdgcn_update_dpp(0, __builtin_bit_cast(int, x), CTRL, 0xF, 0xF, true));
}
// 16-lane (row) reductions via DPP: xor1, xor2, ror4, ror8 — zero DS ops
__device__ inline float rmax16(float x){
  x = fmaxf(x, dppf<0xB1>(x));
  x = fmaxf(x, dppf<0x4E>(x));
  x = fmaxf(x, dppf<0x124>(x));
  x = fmaxf(x, dppf<0x128>(x));
  return x;
}
__device__ inline float rsum16(float x){
  x += dppf<0xB1>(x);
  x += dppf<0x4E>(x);
  x += dppf<0x124>(x);
  x += dppf<0x128>(x);
  return x;
}

// ---------------- kernel 0: weights -> bf16, transposed [out][in], chunk-swizzled ----------------
__global__ __launch_bounds__(256) void prep_w(const float* __restrict__ W1, const float* __restrict__ Wq,
                                              const float* __restrict__ Wk, const float* __restrict__ Wv,
                                              unsigned short* __restrict__ wt){
  int w = blockIdx.x >> 2, qtr = blockIdx.x & 3;
  const float* W = (w==0)?W1:((w==1)?Wq:((w==2)?Wk:Wv));
  unsigned short* dst = wt + w*16384;
  int c = threadIdx.x & 127;
  int khalf = threadIdx.x >> 7;
  int kbase = qtr*32 + khalf*16;
  unsigned short tmp[16];
  #pragma unroll
  for (int i=0;i<16;i++) tmp[i] = f2bf(W[(kbase+i)*128 + c]);
  #pragma unroll
  for (int h=0;h<2;h++){
    int k0 = kbase + h*8;
    int chunk = (k0 >> 3) ^ (c & 7);
    bf16x8 pk;
    #pragma unroll
    for (int j=0;j<8;j++) pk[j] = (short)tmp[h*8+j];
    *reinterpret_cast<bf16x8*>(dst + c*128 + chunk*8) = pk;
  }
}

// ---------------- kernel 0b: adj (f32 0/1) -> bitmask u32[tok][64] ----------------
__global__ __launch_bounds__(256) void prep_mask(const float* __restrict__ adj, u32* __restrict__ mask){
  __shared__ unsigned char nib[4][512];
  int tid = threadIdx.x;
  int lane = tid & 63, wid = tid >> 6;
  int row = blockIdx.x*4 + wid;                 // one wave per row of 2048
  const float* ap = adj + (size_t)row*2048;
  unsigned char* nb = nib[wid];
  #pragma unroll
  for (int k=0;k<8;k++){
    const float4 v = *reinterpret_cast<const float4*>(ap + (lane + k*64)*4);
    u32 n = (v.x!=0.f ? 1u:0u) | (v.y!=0.f ? 2u:0u) | (v.z!=0.f ? 4u:0u) | (v.w!=0.f ? 8u:0u);
    nb[lane + k*64] = (unsigned char)n;
  }
  __syncthreads();
  u32 lo = *reinterpret_cast<const u32*>(nb + lane*8);
  u32 hi = *reinterpret_cast<const u32*>(nb + lane*8 + 4);
  u32 w = (lo & 0xFu) | ((lo>>4)&0xF0u) | ((lo>>8)&0xF00u) | ((lo>>12)&0xF000u);
  u32 wh = (hi & 0xFu) | ((hi>>4)&0xF0u) | ((hi>>8)&0xF00u) | ((hi>>12)&0xF000u);
  mask[(size_t)row*64 + lane] = w | (wh << 16);
}

// ---------------- kernel 1: res = q@W1 ; qh/kh/vh = res@{Wq,Wk,Wv} ----------------
__global__ __launch_bounds__(256,1) void proj(const float* __restrict__ q, const unsigned short* __restrict__ wt,
                                              float* __restrict__ out,
                                              unsigned short* __restrict__ qh, unsigned short* __restrict__ khsw,
                                              unsigned short* __restrict__ vht){
  __shared__ unsigned short sW[4*128*128];   // 128 KB, [w][c][k chunk-swizzled]
  __shared__ unsigned short sX[64*128];      // 16 KB, rows chunk-swizzled (q, then res)
  unsigned short* sVh = sW;                  // alias: reuse W1 region after GEMM1

  int tid = threadIdx.x;
  int lane = tid & 63, wid = tid >> 6;
  int l15 = lane & 15, lg = lane >> 4;
  int rowbase = blockIdx.x * 64;

  #pragma unroll
  for (int p=0;p<32;p++)
    gld16((const char*)wt + p*4096 + tid*16, (const char*)sW + p*4096 + wid*1024);

  {
    int r = tid >> 2, cg = tid & 3;
    const float* qp = q + (size_t)(rowbase + r)*128 + cg*32;
    #pragma unroll
    for (int c8=0;c8<4;c8++){
      bf16x8 pk;
      #pragma unroll
      for (int j=0;j<8;j++) pk[j] = (short)f2bf(qp[c8*8 + j]);
      int chunk = (cg*4 + c8) ^ (r & 7);
      *reinterpret_cast<bf16x8*>(sX + r*128 + chunk*8) = pk;
    }
  }
  __syncthreads();

  auto gemm = [&](const unsigned short* sA, const unsigned short* sB, f32x4 acc[8]){
    #pragma unroll
    for (int ct=0;ct<8;ct++) acc[ct] = (f32x4){0.f,0.f,0.f,0.f};
    #pragma unroll
    for (int kt=0;kt<4;kt++){
      int ar = wid*16 + l15;
      bf16x8 a = *reinterpret_cast<const bf16x8*>(sA + ar*128 + (((kt*4+lg) ^ (ar&7))*8));
      #pragma unroll
      for (int ct=0;ct<8;ct++){
        int cc = ct*16 + l15;
        bf16x8 bb = *reinterpret_cast<const bf16x8*>(sB + cc*128 + (((kt*4+lg) ^ (cc&7))*8));
        acc[ct] = __builtin_amdgcn_mfma_f32_16x16x32_bf16(a, bb, acc[ct], 0, 0, 0);
      }
    }
  };

  f32x4 acc[8];

  // GEMM1: res
  gemm(sX, sW, acc);
  #pragma unroll
  for (int ct=0;ct<8;ct++)
    #pragma unroll
    for (int i=0;i<4;i++){
      int r = wid*16 + lg*4 + i, c = ct*16 + l15;
      int rg = rowbase + r;
      float v = acc[ct][i];
      out[rg*256 + 128 + c] = v;
      out[TOK*256 + rg*128 + c] = v;
    }
  __syncthreads();
  #pragma unroll
  for (int ct=0;ct<8;ct++)
    #pragma unroll
    for (int i=0;i<4;i++){
      int r = wid*16 + lg*4 + i, c = ct*16 + l15;
      sX[r*128 + (((c>>3) ^ (r&7))*8) + (c&7)] = f2bf(acc[ct][i]);
    }
  __syncthreads();

  // GEMM2: qh, fold (1/sqrt(128)) * log2(e)  -> exp2-domain softmax
  gemm(sX, sW + 16384, acc);
  const float SCALE = 0.12751742f;
  #pragma unroll
  for (int ct=0;ct<8;ct++)
    #pragma unroll
    for (int i=0;i<4;i++){
      int r = wid*16 + lg*4 + i, c = ct*16 + l15;
      qh[(rowbase + r)*128 + c] = f2bf(acc[ct][i]*SCALE);
    }

  // GEMM3: kh, row-chunk-swizzled for conflict-free ds_read_b128
  gemm(sX, sW + 2*16384, acc);
  #pragma unroll
  for (int ct=0;ct<8;ct++)
    #pragma unroll
    for (int i=0;i<4;i++){
      int r = wid*16 + lg*4 + i, c = ct*16 + l15;
      int rg = rowbase + r;
      khsw[rg*128 + (c ^ ((rg&7)<<3))] = f2bf(acc[ct][i]);
    }

  // GEMM4: vh -> LDS -> plain transposed [b][feat][n] global write
  gemm(sX, sW + 3*16384, acc);
  #pragma unroll
  for (int ct=0;ct<8;ct++)
    #pragma unroll
    for (int i=0;i<4;i++){
      int r = wid*16 + lg*4 + i, c = ct*16 + l15;
      sVh[r*130 + c] = f2bf(acc[ct][i]);
    }
  __syncthreads();
  {
    int bb = rowbase >> 11;
    int n0 = rowbase & 2047;
    #pragma unroll
    for (int it=0; it<4; ++it){
      int idx = tid + it*256;
      int f = idx >> 3, ch = idx & 7;
      bf16x8 pk;
      #pragma unroll
      for (int j=0;j<8;j++) pk[j] = (short)sVh[(ch*8+j)*130 + f];
      int ci = (n0 >> 3) + ch;
      *reinterpret_cast<bf16x8*>(vht + bb*(DIM*SEQ) + f*SEQ + ci*8) = pk;
    }
  }
}

// ---------------- kernel 2: flash attention, bitmask, KVBLK=64 ----------------
__global__ __launch_bounds__(256,2) void attn(const unsigned short* __restrict__ qh,
                                              const unsigned short* __restrict__ khsw,
                                              const unsigned short* __restrict__ vht,
                                              const u32* __restrict__ mask,
                                              float* __restrict__ out){
  __shared__ unsigned short sK[2][64*128];   // [kv][feat], rows chunk-XOR swizzled (16 KB ea)
  __shared__ unsigned short sV[2][128*64];   // [feat][kv], chunk-XOR swizzled (16 KB ea)
  __shared__ u32            sM[2][128];      // 64 rows x 2 words
  __shared__ unsigned short sP[4][16*72];    // per-wave P, rows padded to 144 B

  const int tid = threadIdx.x;
  const int lane = tid & 63, wid = tid >> 6;
  const int l15 = lane & 15, lg = lane >> 4;
  const int bfid = blockIdx.x;
  const int b = bfid & 7, qblk = bfid >> 3;   // batch -> XCD affinity
  const int qbase = qblk * 64;
  const int tokbase = b*SEQ + qbase;
  const unsigned short* vhb = vht + (size_t)b*DIM*SEQ;
  const u32* mb = mask + (size_t)tokbase*64;

  // Q fragments: wave owns rows [wid*16, wid*16+16); scale+log2e pre-folded
  bf16x8 qf[4];
  {
    const unsigned short* qp = qh + (size_t)(tokbase + wid*16 + l15)*128;
    #pragma unroll
    for (int kt=0;kt<4;kt++) qf[kt] = *reinterpret_cast<const bf16x8*>(qp + kt*32 + lg*8);
  }

  f32x4 o[8];
  #pragma unroll
  for (int ct=0;ct<8;ct++) o[ct] = (f32x4){0.f,0.f,0.f,0.f};
  float mrow[4], lrow[4];
  #pragma unroll
  for (int i=0;i<4;i++){ mrow[i] = -3e38f; lrow[i] = 0.f; }

  auto stage = [&](int tt, int db){
    const char* kbase = (const char*)(khsw + (size_t)(b*SEQ + tt*64)*128);
    #pragma unroll
    for (int p=0;p<4;p++)
      gld16(kbase + p*4096 + tid*16, (const char*)sK[db] + p*4096 + wid*1024);
    #pragma unroll
    for (int p=0;p<4;p++){
      int u = p*256 + tid;
      int ff = u >> 3, cp = u & 7;
      gld16(vhb + (size_t)ff*SEQ + tt*64 + ((cp ^ (ff&7))*8),   // pre-swizzled per-lane SOURCE
            (const char*)sV[db] + p*4096 + wid*1024);
    }
    if (tid < 128)
      gld4(mb + (tid>>1)*64 + tt*2 + (tid&1), (const char*)sM[db] + (tid>>6)*256);
  };

  stage(0, 0);
  __syncthreads();

  for (int t=0; t<32; ++t){
    const int db = t & 1;
    if (t+1 < 32) stage(t+1, db^1);

    const unsigned short* K = sK[db];
    const unsigned short* V = sV[db];
    const u32* M = sM[db];

    // S = Q K^T : 16 rows x 64 kv
    f32x4 s[4];
    #pragma unroll
    for (int ct=0;ct<4;ct++) s[ct] = (f32x4){0.f,0.f,0.f,0.f};
    #pragma unroll
    for (int kt=0;kt<4;kt++){
      #pragma unroll
      for (int ct=0;ct<4;ct++){
        int kr = ct*16 + l15;
        bf16x8 kf = *reinterpret_cast<const bf16x8*>(K + kr*128 + (((kt*4+lg) ^ (kr&7))*8));
        s[ct] = __builtin_amdgcn_mfma_f32_16x16x32_bf16(qf[kt], kf, s[ct], 0,0,0);
      }
    }

    // mask from bits
    #pragma unroll
    for (int i=0;i<4;i++){
      int r = wid*16 + lg*4 + i;
      u32 m0 = M[r*2], m1 = M[r*2+1];
      #pragma unroll
      for (int ct=0;ct<4;ct++){
        u32 w = (ct < 2) ? m0 : m1;
        u32 bit = (w >> ((ct&1)*16 + l15)) & 1u;
        s[ct][i] = bit ? s[ct][i] : -1e9f;
      }
    }

    // online softmax in exp2 domain, defer-max THR=8
    #pragma unroll
    for (int i=0;i<4;i++){
      float pm = fmaxf(fmaxf(s[0][i], s[1][i]), fmaxf(s[2][i], s[3][i]));
      pm = rmax16(pm);
      if (__any(pm > mrow[i] + 8.f)){
        float nm = fmaxf(mrow[i], pm);
        float scv = exp2f(mrow[i] - nm);
        mrow[i] = nm;
        lrow[i] *= scv;
        #pragma unroll
        for (int ct=0;ct<8;ct++) o[ct][i] *= scv;
      }
      float p0 = exp2f(s[0][i] - mrow[i]);
      float p1 = exp2f(s[1][i] - mrow[i]);
      float p2 = exp2f(s[2][i] - mrow[i]);
      float p3 = exp2f(s[3][i] - mrow[i]);
      s[0][i]=p0; s[1][i]=p1; s[2][i]=p2; s[3][i]=p3;
      lrow[i] += rsum16(p0+p1+p2+p3);
    }

    // P -> per-wave LDS (C-layout -> A-layout)
    unsigned short* Pw = sP[wid];
    #pragma unroll
    for (int ct=0;ct<4;ct++)
      #pragma unroll
      for (int i=0;i<4;i++)
        Pw[(lg*4+i)*72 + ct*16 + l15] = f2bf(s[ct][i]);
    bf16x8 pa[2];
    #pragma unroll
    for (int sl=0;sl<2;sl++)
      pa[sl] = *reinterpret_cast<const bf16x8*>(Pw + l15*72 + sl*32 + lg*8);

    // O += P V
    #pragma unroll
    for (int ct=0;ct<8;ct++){
      int ff = ct*16 + l15;
      bf16x8 v0 = *reinterpret_cast<const bf16x8*>(V + ff*64 + ((lg ^ (ff&7))*8));
      bf16x8 v1 = *reinterpret_cast<const bf16x8*>(V + ff*64 + (((4+lg) ^ (ff&7))*8));
      o[ct] = __builtin_amdgcn_mfma_f32_16x16x32_bf16(pa[0], v0, o[ct], 0,0,0);
      o[ct] = __builtin_amdgcn_mfma_f32_16x16x32_bf16(pa[1], v1, o[ct], 0,0,0);
    }
    __syncthreads();
  }

  float inv[4];
  #pragma unroll
  for (int i=0;i<4;i++) inv[i] = 1.0f / lrow[i];
  #pragma unroll
  for (int ct=0;ct<8;ct++)
    #pragma unroll
    for (int i=0;i<4;i++)
      out[(size_t)(tokbase + wid*16 + lg*4 + i)*256 + ct*16 + l15] = o[ct][i]*inv[i];
}

extern "C" void kernel_launch(void* const* d_in, const int* in_sizes, int n_in,
                              void* d_out, int out_size, void* d_ws, size_t ws_size,
                              hipStream_t stream){
  (void)in_sizes; (void)n_in; (void)out_size; (void)ws_size;
  const float* q   = (const float*)d_in[0];
  const float* adj = (const float*)d_in[3];
  const float* W1  = (const float*)d_in[4];
  const float* Wq  = (const float*)d_in[5];
  const float* Wk  = (const float*)d_in[6];
  const float* Wv  = (const float*)d_in[7];
  float* out = (float*)d_out;

  unsigned short* qh = (unsigned short*)d_ws;      // 4 MB
  unsigned short* kh = qh + (size_t)TOK*DIM;       // 4 MB (pre-swizzled rows)
  unsigned short* vh = kh + (size_t)TOK*DIM;       // 4 MB (transposed per batch)
  unsigned short* wt = vh + (size_t)TOK*DIM;       // 128 KB
  u32*            mk = (u32*)(wt + 4*128*128);     // 4 MB bitmask

  prep_w   <<<16,   256, 0, stream>>>(W1, Wq, Wk, Wv, wt);
  prep_mask<<<4096, 256, 0, stream>>>(adj, mk);
  proj     <<<256,  256, 0, stream>>>(q, wt, out, qh, kh, vh);
  attn     <<<256,  256, 0, stream>>>(qh, kh, vh, mk, out);
}

// Round 3
// 92.247 us; speedup vs baseline: 1.3268x; 1.2100x over previous
//
#include <hip/hip_runtime.h>

typedef __attribute__((ext_vector_type(8))) short bf16x8;
typedef __attribute__((ext_vector_type(4))) float f32x4;
typedef unsigned int u32;

#define TOK 16384
#define DIM 128
#define SEQ 2048

__device__ inline unsigned short f2bf(float f){
  union { float f; u32 u; } v; v.f = f;
  u32 r = v.u + 0x7fffu + ((v.u >> 16) & 1u);
  return (unsigned short)(r >> 16);
}
__device__ inline float bf2f(unsigned short u){
  union { u32 u; float f; } v; v.u = ((u32)u) << 16;
  return v.f;
}

__device__ inline void gld16(const void* g, const void* l){
  __builtin_amdgcn_global_load_lds((const __attribute__((address_space(1))) void*)g,
                                   (__attribute__((address_space(3))) void*)l, 16, 0, 0);
}
__device__ inline void gld4(const void* g, const void* l){
  __builtin_amdgcn_global_load_lds((const __attribute__((address_space(1))) void*)g,
                                   (__attribute__((address_space(3))) void*)l, 4, 0, 0);
}

template<int CTRL>
__device__ inline float dppf(float x){
  return __builtin_bit_cast(float,
    __builtin_amdgcn_update_dpp(0, __builtin_bit_cast(int, x), CTRL, 0xF, 0xF, true));
}
__device__ inline float rmax16(float x){
  x = fmaxf(x, dppf<0xB1>(x));
  x = fmaxf(x, dppf<0x4E>(x));
  x = fmaxf(x, dppf<0x124>(x));
  x = fmaxf(x, dppf<0x128>(x));
  return x;
}
__device__ inline float rsum16(float x){
  x += dppf<0xB1>(x);
  x += dppf<0x4E>(x);
  x += dppf<0x124>(x);
  x += dppf<0x128>(x);
  return x;
}

// ---------------- kernel 0: weights -> bf16, transposed [out][in], chunk-swizzled ----------------
__global__ __launch_bounds__(256) void prep_w(const float* __restrict__ W1, const float* __restrict__ Wq,
                                              const float* __restrict__ Wk, const float* __restrict__ Wv,
                                              unsigned short* __restrict__ wt){
  int w = blockIdx.x >> 2, qtr = blockIdx.x & 3;
  const float* W = (w==0)?W1:((w==1)?Wq:((w==2)?Wk:Wv));
  unsigned short* dst = wt + w*16384;
  int c = threadIdx.x & 127;
  int khalf = threadIdx.x >> 7;
  int kbase = qtr*32 + khalf*16;
  unsigned short tmp[16];
  #pragma unroll
  for (int i=0;i<16;i++) tmp[i] = f2bf(W[(kbase+i)*128 + c]);
  #pragma unroll
  for (int h=0;h<2;h++){
    int k0 = kbase + h*8;
    int chunk = (k0 >> 3) ^ (c & 7);
    bf16x8 pk;
    #pragma unroll
    for (int j=0;j<8;j++) pk[j] = (short)tmp[h*8+j];
    *reinterpret_cast<bf16x8*>(dst + c*128 + chunk*8) = pk;
  }
}

// ---------------- kernel 0b: adj (f32 0/1) -> bitmask u32[tok][64] ----------------
__global__ __launch_bounds__(256) void prep_mask(const float* __restrict__ adj, u32* __restrict__ mask){
  __shared__ unsigned char nib[4][512];
  int tid = threadIdx.x;
  int lane = tid & 63, wid = tid >> 6;
  int row = blockIdx.x*4 + wid;
  const float* ap = adj + (size_t)row*2048;
  unsigned char* nb = nib[wid];
  #pragma unroll
  for (int k=0;k<8;k++){
    const float4 v = *reinterpret_cast<const float4*>(ap + (lane + k*64)*4);
    u32 n = (v.x!=0.f ? 1u:0u) | (v.y!=0.f ? 2u:0u) | (v.z!=0.f ? 4u:0u) | (v.w!=0.f ? 8u:0u);
    nb[lane + k*64] = (unsigned char)n;
  }
  __syncthreads();
  u32 lo = *reinterpret_cast<const u32*>(nb + lane*8);
  u32 hi = *reinterpret_cast<const u32*>(nb + lane*8 + 4);
  u32 w = (lo & 0xFu) | ((lo>>4)&0xF0u) | ((lo>>8)&0xF00u) | ((lo>>12)&0xF000u);
  u32 wh = (hi & 0xFu) | ((hi>>4)&0xF0u) | ((hi>>8)&0xF00u) | ((hi>>12)&0xF000u);
  mask[(size_t)row*64 + lane] = w | (wh << 16);
}

// ---------------- kernel 1: res = q@W1 ; qh/kh/vh = res@{Wq,Wk,Wv} ----------------
__global__ __launch_bounds__(256,1) void proj(const float* __restrict__ q, const unsigned short* __restrict__ wt,
                                              float* __restrict__ out,
                                              unsigned short* __restrict__ qh, unsigned short* __restrict__ khsw,
                                              unsigned short* __restrict__ vht){
  __shared__ unsigned short sW[4*128*128];
  __shared__ unsigned short sX[64*128];
  unsigned short* sVh = sW;

  int tid = threadIdx.x;
  int lane = tid & 63, wid = tid >> 6;
  int l15 = lane & 15, lg = lane >> 4;
  int rowbase = blockIdx.x * 64;

  #pragma unroll
  for (int p=0;p<32;p++)
    gld16((const char*)wt + p*4096 + tid*16, (const char*)sW + p*4096 + wid*1024);

  {
    int r = tid >> 2, cg = tid & 3;
    const float* qp = q + (size_t)(rowbase + r)*128 + cg*32;
    #pragma unroll
    for (int c8=0;c8<4;c8++){
      bf16x8 pk;
      #pragma unroll
      for (int j=0;j<8;j++) pk[j] = (short)f2bf(qp[c8*8 + j]);
      int chunk = (cg*4 + c8) ^ (r & 7);
      *reinterpret_cast<bf16x8*>(sX + r*128 + chunk*8) = pk;
    }
  }
  __syncthreads();

  auto gemm = [&](const unsigned short* sA, const unsigned short* sB, f32x4 acc[8]){
    #pragma unroll
    for (int ct=0;ct<8;ct++) acc[ct] = (f32x4){0.f,0.f,0.f,0.f};
    #pragma unroll
    for (int kt=0;kt<4;kt++){
      int ar = wid*16 + l15;
      bf16x8 a = *reinterpret_cast<const bf16x8*>(sA + ar*128 + (((kt*4+lg) ^ (ar&7))*8));
      #pragma unroll
      for (int ct=0;ct<8;ct++){
        int cc = ct*16 + l15;
        bf16x8 bb = *reinterpret_cast<const bf16x8*>(sB + cc*128 + (((kt*4+lg) ^ (cc&7))*8));
        acc[ct] = __builtin_amdgcn_mfma_f32_16x16x32_bf16(a, bb, acc[ct], 0, 0, 0);
      }
    }
  };

  f32x4 acc[8];

  // GEMM1: res
  gemm(sX, sW, acc);
  #pragma unroll
  for (int ct=0;ct<8;ct++)
    #pragma unroll
    for (int i=0;i<4;i++){
      int r = wid*16 + lg*4 + i, c = ct*16 + l15;
      int rg = rowbase + r;
      float v = acc[ct][i];
      out[rg*256 + 128 + c] = v;
      out[TOK*256 + rg*128 + c] = v;
    }
  __syncthreads();
  #pragma unroll
  for (int ct=0;ct<8;ct++)
    #pragma unroll
    for (int i=0;i<4;i++){
      int r = wid*16 + lg*4 + i, c = ct*16 + l15;
      sX[r*128 + (((c>>3) ^ (r&7))*8) + (c&7)] = f2bf(acc[ct][i]);
    }
  __syncthreads();

  // GEMM2: qh, fold (1/sqrt(128)) * log2(e)
  gemm(sX, sW + 16384, acc);
  const float SCALE = 0.12751742f;
  #pragma unroll
  for (int ct=0;ct<8;ct++)
    #pragma unroll
    for (int i=0;i<4;i++){
      int r = wid*16 + lg*4 + i, c = ct*16 + l15;
      qh[(rowbase + r)*128 + c] = f2bf(acc[ct][i]*SCALE);
    }

  // GEMM3: kh, row-chunk-swizzled
  gemm(sX, sW + 2*16384, acc);
  #pragma unroll
  for (int ct=0;ct<8;ct++)
    #pragma unroll
    for (int i=0;i<4;i++){
      int r = wid*16 + lg*4 + i, c = ct*16 + l15;
      int rg = rowbase + r;
      khsw[rg*128 + (c ^ ((rg&7)<<3))] = f2bf(acc[ct][i]);
    }

  // GEMM4: vh -> transposed [b][feat][n]
  gemm(sX, sW + 3*16384, acc);
  #pragma unroll
  for (int ct=0;ct<8;ct++)
    #pragma unroll
    for (int i=0;i<4;i++){
      int r = wid*16 + lg*4 + i, c = ct*16 + l15;
      sVh[r*130 + c] = f2bf(acc[ct][i]);
    }
  __syncthreads();
  {
    int bb = rowbase >> 11;
    int n0 = rowbase & 2047;
    #pragma unroll
    for (int it=0; it<4; ++it){
      int idx = tid + it*256;
      int f = idx >> 3, ch = idx & 7;
      bf16x8 pk;
      #pragma unroll
      for (int j=0;j<8;j++) pk[j] = (short)sVh[(ch*8+j)*130 + f];
      int ci = (n0 >> 3) + ch;
      *reinterpret_cast<bf16x8*>(vht + bb*(DIM*SEQ) + f*SEQ + ci*8) = pk;
    }
  }
}

// ---------------- kernel 2: flash attention, split-KV x2, partials out ----------------
__global__ __launch_bounds__(256,2) void attn(const unsigned short* __restrict__ qh,
                                              const unsigned short* __restrict__ khsw,
                                              const unsigned short* __restrict__ vht,
                                              const u32* __restrict__ mask,
                                              unsigned short* __restrict__ po,
                                              float* __restrict__ pml){
  __shared__ unsigned short sK[2][64*128];
  __shared__ unsigned short sV[2][128*64];
  __shared__ u32            sM[2][128];
  __shared__ unsigned short sP[4][16*72];

  const int tid = threadIdx.x;
  const int lane = tid & 63, wid = tid >> 6;
  const int l15 = lane & 15, lg = lane >> 4;
  const int bfid = blockIdx.x;
  const int half = bfid >> 8;
  const int rest = bfid & 255;
  const int b = rest & 7, qblk = rest >> 3;     // bfid%8 == b for both halves -> same XCD
  const int qbase = qblk * 64;
  const int tokbase = b*SEQ + qbase;
  const int kvbase = half * 1024;
  const unsigned short* vhb = vht + (size_t)b*DIM*SEQ;
  const u32* mb = mask + (size_t)tokbase*64 + (kvbase >> 5);

  bf16x8 qf[4];
  {
    const unsigned short* qp = qh + (size_t)(tokbase + wid*16 + l15)*128;
    #pragma unroll
    for (int kt=0;kt<4;kt++) qf[kt] = *reinterpret_cast<const bf16x8*>(qp + kt*32 + lg*8);
  }

  f32x4 o[8];
  #pragma unroll
  for (int ct=0;ct<8;ct++) o[ct] = (f32x4){0.f,0.f,0.f,0.f};
  float mrow[4], lrow[4];
  #pragma unroll
  for (int i=0;i<4;i++){ mrow[i] = -3e38f; lrow[i] = 0.f; }

  auto stage = [&](int tt, int db){
    const char* kbase = (const char*)(khsw + (size_t)(b*SEQ + kvbase + tt*64)*128);
    #pragma unroll
    for (int p=0;p<4;p++)
      gld16(kbase + p*4096 + tid*16, (const char*)sK[db] + p*4096 + wid*1024);
    #pragma unroll
    for (int p=0;p<4;p++){
      int u = p*256 + tid;
      int ff = u >> 3, cp = u & 7;
      gld16(vhb + (size_t)ff*SEQ + kvbase + tt*64 + ((cp ^ (ff&7))*8),
            (const char*)sV[db] + p*4096 + wid*1024);
    }
    if (tid < 128)
      gld4(mb + (tid>>1)*64 + tt*2 + (tid&1), (const char*)sM[db] + (tid>>6)*256);
  };

  stage(0, 0);
  __syncthreads();

  for (int t=0; t<16; ++t){
    const int db = t & 1;
    if (t+1 < 16) stage(t+1, db^1);

    const unsigned short* K = sK[db];
    const unsigned short* V = sV[db];
    const u32* M = sM[db];

    // S = Q K^T
    f32x4 s[4];
    #pragma unroll
    for (int ct=0;ct<4;ct++) s[ct] = (f32x4){0.f,0.f,0.f,0.f};
    #pragma unroll
    for (int kt=0;kt<4;kt++){
      #pragma unroll
      for (int ct=0;ct<4;ct++){
        int kr = ct*16 + l15;
        bf16x8 kf = *reinterpret_cast<const bf16x8*>(K + kr*128 + (((kt*4+lg) ^ (kr&7))*8));
        s[ct] = __builtin_amdgcn_mfma_f32_16x16x32_bf16(qf[kt], kf, s[ct], 0,0,0);
      }
    }

    // mask bits
    #pragma unroll
    for (int i=0;i<4;i++){
      int r = wid*16 + lg*4 + i;
      u32 m0 = M[r*2], m1 = M[r*2+1];
      #pragma unroll
      for (int ct=0;ct<4;ct++){
        u32 w = (ct < 2) ? m0 : m1;
        u32 bit = (w >> ((ct&1)*16 + l15)) & 1u;
        s[ct][i] = bit ? s[ct][i] : -1e9f;
      }
    }

    // online softmax (exp2 domain), defer-max THR=8
    #pragma unroll
    for (int i=0;i<4;i++){
      float pm = fmaxf(fmaxf(s[0][i], s[1][i]), fmaxf(s[2][i], s[3][i]));
      pm = rmax16(pm);
      if (__any(pm > mrow[i] + 8.f)){
        float nm = fmaxf(mrow[i], pm);
        float scv = exp2f(mrow[i] - nm);
        mrow[i] = nm;
        lrow[i] *= scv;
        #pragma unroll
        for (int ct=0;ct<8;ct++) o[ct][i] *= scv;
      }
      float p0 = exp2f(s[0][i] - mrow[i]);
      float p1 = exp2f(s[1][i] - mrow[i]);
      float p2 = exp2f(s[2][i] - mrow[i]);
      float p3 = exp2f(s[3][i] - mrow[i]);
      s[0][i]=p0; s[1][i]=p1; s[2][i]=p2; s[3][i]=p3;
      lrow[i] += rsum16(p0+p1+p2+p3);
    }

    // P -> per-wave LDS (C-layout -> A-layout)
    unsigned short* Pw = sP[wid];
    #pragma unroll
    for (int ct=0;ct<4;ct++)
      #pragma unroll
      for (int i=0;i<4;i++)
        Pw[(lg*4+i)*72 + ct*16 + l15] = f2bf(s[ct][i]);
    bf16x8 pa[2];
    #pragma unroll
    for (int sl=0;sl<2;sl++)
      pa[sl] = *reinterpret_cast<const bf16x8*>(Pw + l15*72 + sl*32 + lg*8);

    // O += P V
    #pragma unroll
    for (int ct=0;ct<8;ct++){
      int ff = ct*16 + l15;
      bf16x8 v0 = *reinterpret_cast<const bf16x8*>(V + ff*64 + ((lg ^ (ff&7))*8));
      bf16x8 v1 = *reinterpret_cast<const bf16x8*>(V + ff*64 + (((4+lg) ^ (ff&7))*8));
      o[ct] = __builtin_amdgcn_mfma_f32_16x16x32_bf16(pa[0], v0, o[ct], 0,0,0);
      o[ct] = __builtin_amdgcn_mfma_f32_16x16x32_bf16(pa[1], v1, o[ct], 0,0,0);
    }
    __syncthreads();
  }

  // write unnormalized partials + (m,l)
  #pragma unroll
  for (int ct=0;ct<8;ct++)
    #pragma unroll
    for (int i=0;i<4;i++){
      int row = tokbase + wid*16 + lg*4 + i;
      po[(size_t)(half*TOK + row)*128 + ct*16 + l15] = f2bf(o[ct][i]);
    }
  if (l15 == 0){
    #pragma unroll
    for (int i=0;i<4;i++){
      int row = tokbase + wid*16 + lg*4 + i;
      pml[(size_t)row*4 + half*2 + 0] = mrow[i];
      pml[(size_t)row*4 + half*2 + 1] = lrow[i];
    }
  }
}

// ---------------- kernel 3: merge split-KV partials ----------------
__global__ __launch_bounds__(256) void merge(const unsigned short* __restrict__ po,
                                             const float* __restrict__ pml,
                                             float* __restrict__ out){
  const int mblk = blockIdx.x;
  const int b = mblk & 7, qblk = mblk >> 3;     // same XCD as producers
  const int tokbase = b*SEQ + qblk*64;
  const int tid = threadIdx.x;
  const int row = tokbase + (tid >> 2);
  const int c0 = (tid & 3) * 32;

  f32x4 ml = *reinterpret_cast<const f32x4*>(pml + (size_t)row*4);
  float M = fmaxf(ml[0], ml[2]);
  float a0 = exp2f(ml[0] - M), a1 = exp2f(ml[2] - M);
  float inv = 1.f / (ml[1]*a0 + ml[3]*a1);
  a0 *= inv; a1 *= inv;

  const unsigned short* p0 = po + (size_t)row*128 + c0;
  const unsigned short* p1 = po + (size_t)(TOK + row)*128 + c0;
  float* op = out + (size_t)row*256 + c0;
  #pragma unroll
  for (int k=0;k<4;k++){
    bf16x8 v0 = *reinterpret_cast<const bf16x8*>(p0 + k*8);
    bf16x8 v1 = *reinterpret_cast<const bf16x8*>(p1 + k*8);
    float4 r0, r1;
    r0.x = bf2f((unsigned short)v0[0])*a0 + bf2f((unsigned short)v1[0])*a1;
    r0.y = bf2f((unsigned short)v0[1])*a0 + bf2f((unsigned short)v1[1])*a1;
    r0.z = bf2f((unsigned short)v0[2])*a0 + bf2f((unsigned short)v1[2])*a1;
    r0.w = bf2f((unsigned short)v0[3])*a0 + bf2f((unsigned short)v1[3])*a1;
    r1.x = bf2f((unsigned short)v0[4])*a0 + bf2f((unsigned short)v1[4])*a1;
    r1.y = bf2f((unsigned short)v0[5])*a0 + bf2f((unsigned short)v1[5])*a1;
    r1.z = bf2f((unsigned short)v0[6])*a0 + bf2f((unsigned short)v1[6])*a1;
    r1.w = bf2f((unsigned short)v0[7])*a0 + bf2f((unsigned short)v1[7])*a1;
    *reinterpret_cast<float4*>(op + k*8)     = r0;
    *reinterpret_cast<float4*>(op + k*8 + 4) = r1;
  }
}

extern "C" void kernel_launch(void* const* d_in, const int* in_sizes, int n_in,
                              void* d_out, int out_size, void* d_ws, size_t ws_size,
                              hipStream_t stream){
  (void)in_sizes; (void)n_in; (void)out_size; (void)ws_size;
  const float* q   = (const float*)d_in[0];
  const float* adj = (const float*)d_in[3];
  const float* W1  = (const float*)d_in[4];
  const float* Wq  = (const float*)d_in[5];
  const float* Wk  = (const float*)d_in[6];
  const float* Wv  = (const float*)d_in[7];
  float* out = (float*)d_out;

  unsigned short* qh = (unsigned short*)d_ws;        // 4 MB
  unsigned short* kh = qh + (size_t)TOK*DIM;         // 4 MB
  unsigned short* vh = kh + (size_t)TOK*DIM;         // 4 MB
  unsigned short* wt = vh + (size_t)TOK*DIM;         // 128 KB
  u32*            mk = (u32*)(wt + 4*128*128);       // 4 MB
  unsigned short* po = (unsigned short*)(mk + (size_t)TOK*64);  // 8 MB (2 x bf16 partial O)
  float*          pml = (float*)(po + (size_t)2*TOK*DIM);       // 256 KB

  prep_w   <<<16,   256, 0, stream>>>(W1, Wq, Wk, Wv, wt);
  prep_mask<<<4096, 256, 0, stream>>>(adj, mk);
  proj     <<<256,  256, 0, stream>>>(q, wt, out, qh, kh, vh);
  attn     <<<512,  256, 0, stream>>>(qh, kh, vh, mk, po, pml);
  merge    <<<256,  256, 0, stream>>>(po, pml, out);
}

// Round 4
// 81.229 us; speedup vs baseline: 1.5068x; 1.1356x over previous
//
#include <hip/hip_runtime.h>

typedef __attribute__((ext_vector_type(8))) short bf16x8;
typedef __attribute__((ext_vector_type(4))) float f32x4;
typedef unsigned int u32;

#define TOK 16384
#define DIM 128
#define SEQ 2048

__device__ inline unsigned short f2bf(float f){
  union { float f; u32 u; } v; v.f = f;
  u32 r = v.u + 0x7fffu + ((v.u >> 16) & 1u);
  return (unsigned short)(r >> 16);
}
__device__ inline float bf2f(unsigned short u){
  union { u32 u; float f; } v; v.u = ((u32)u) << 16;
  return v.f;
}

__device__ inline void gld16(const void* g, const void* l){
  __builtin_amdgcn_global_load_lds((const __attribute__((address_space(1))) void*)g,
                                   (__attribute__((address_space(3))) void*)l, 16, 0, 0);
}

template<int CTRL>
__device__ inline float dppf(float x){
  return __builtin_bit_cast(float,
    __builtin_amdgcn_update_dpp(0, __builtin_bit_cast(int, x), CTRL, 0xF, 0xF, true));
}
__device__ inline float rmax16(float x){
  x = fmaxf(x, dppf<0xB1>(x));
  x = fmaxf(x, dppf<0x4E>(x));
  x = fmaxf(x, dppf<0x124>(x));
  x = fmaxf(x, dppf<0x128>(x));
  return x;
}
__device__ inline float rsum16(float x){
  x += dppf<0xB1>(x);
  x += dppf<0x4E>(x);
  x += dppf<0x124>(x);
  x += dppf<0x128>(x);
  return x;
}

// ---------------- kernel 0: weights -> bf16, transposed [out][in], chunk-swizzled ----------------
__global__ __launch_bounds__(256) void prep_w(const float* __restrict__ W1, const float* __restrict__ Wq,
                                              const float* __restrict__ Wk, const float* __restrict__ Wv,
                                              unsigned short* __restrict__ wt){
  int w = blockIdx.x >> 2, qtr = blockIdx.x & 3;
  const float* W = (w==0)?W1:((w==1)?Wq:((w==2)?Wk:Wv));
  unsigned short* dst = wt + w*16384;
  int c = threadIdx.x & 127;
  int khalf = threadIdx.x >> 7;
  int kbase = qtr*32 + khalf*16;
  unsigned short tmp[16];
  #pragma unroll
  for (int i=0;i<16;i++) tmp[i] = f2bf(W[(kbase+i)*128 + c]);
  #pragma unroll
  for (int h=0;h<2;h++){
    int k0 = kbase + h*8;
    int chunk = (k0 >> 3) ^ (c & 7);
    bf16x8 pk;
    #pragma unroll
    for (int j=0;j<8;j++) pk[j] = (short)tmp[h*8+j];
    *reinterpret_cast<bf16x8*>(dst + c*128 + chunk*8) = pk;
  }
}

// ---------------- kernel 1: res = q@W1 ; qh/kh/vh = res@{Wq,Wk,Wv} ----------------
__global__ __launch_bounds__(256,1) void proj(const float* __restrict__ q, const unsigned short* __restrict__ wt,
                                              float* __restrict__ out,
                                              unsigned short* __restrict__ qh, unsigned short* __restrict__ khsw,
                                              unsigned short* __restrict__ vht){
  __shared__ unsigned short sW[4*128*128];
  __shared__ unsigned short sX[64*128];
  unsigned short* sVh = sW;

  int tid = threadIdx.x;
  int lane = tid & 63, wid = tid >> 6;
  int l15 = lane & 15, lg = lane >> 4;
  int rowbase = blockIdx.x * 64;

  #pragma unroll
  for (int p=0;p<32;p++)
    gld16((const char*)wt + p*4096 + tid*16, (const char*)sW + p*4096 + wid*1024);

  {
    int r = tid >> 2, cg = tid & 3;
    const float* qp = q + (size_t)(rowbase + r)*128 + cg*32;
    #pragma unroll
    for (int c8=0;c8<4;c8++){
      bf16x8 pk;
      #pragma unroll
      for (int j=0;j<8;j++) pk[j] = (short)f2bf(qp[c8*8 + j]);
      int chunk = (cg*4 + c8) ^ (r & 7);
      *reinterpret_cast<bf16x8*>(sX + r*128 + chunk*8) = pk;
    }
  }
  __syncthreads();

  auto gemm = [&](const unsigned short* sA, const unsigned short* sB, f32x4 acc[8]){
    #pragma unroll
    for (int ct=0;ct<8;ct++) acc[ct] = (f32x4){0.f,0.f,0.f,0.f};
    #pragma unroll
    for (int kt=0;kt<4;kt++){
      int ar = wid*16 + l15;
      bf16x8 a = *reinterpret_cast<const bf16x8*>(sA + ar*128 + (((kt*4+lg) ^ (ar&7))*8));
      #pragma unroll
      for (int ct=0;ct<8;ct++){
        int cc = ct*16 + l15;
        bf16x8 bb = *reinterpret_cast<const bf16x8*>(sB + cc*128 + (((kt*4+lg) ^ (cc&7))*8));
        acc[ct] = __builtin_amdgcn_mfma_f32_16x16x32_bf16(a, bb, acc[ct], 0, 0, 0);
      }
    }
  };

  f32x4 acc[8];

  // GEMM1: res
  gemm(sX, sW, acc);
  #pragma unroll
  for (int ct=0;ct<8;ct++)
    #pragma unroll
    for (int i=0;i<4;i++){
      int r = wid*16 + lg*4 + i, c = ct*16 + l15;
      int rg = rowbase + r;
      float v = acc[ct][i];
      out[rg*256 + 128 + c] = v;
      out[TOK*256 + rg*128 + c] = v;
    }
  __syncthreads();
  #pragma unroll
  for (int ct=0;ct<8;ct++)
    #pragma unroll
    for (int i=0;i<4;i++){
      int r = wid*16 + lg*4 + i, c = ct*16 + l15;
      sX[r*128 + (((c>>3) ^ (r&7))*8) + (c&7)] = f2bf(acc[ct][i]);
    }
  __syncthreads();

  // GEMM2: qh, fold (1/sqrt(128)) * log2(e)
  gemm(sX, sW + 16384, acc);
  const float SCALE = 0.12751742f;
  #pragma unroll
  for (int ct=0;ct<8;ct++)
    #pragma unroll
    for (int i=0;i<4;i++){
      int r = wid*16 + lg*4 + i, c = ct*16 + l15;
      qh[(rowbase + r)*128 + c] = f2bf(acc[ct][i]*SCALE);
    }

  // GEMM3: kh, row-chunk-swizzled
  gemm(sX, sW + 2*16384, acc);
  #pragma unroll
  for (int ct=0;ct<8;ct++)
    #pragma unroll
    for (int i=0;i<4;i++){
      int r = wid*16 + lg*4 + i, c = ct*16 + l15;
      int rg = rowbase + r;
      khsw[rg*128 + (c ^ ((rg&7)<<3))] = f2bf(acc[ct][i]);
    }

  // GEMM4: vh -> transposed [b][feat][n]
  gemm(sX, sW + 3*16384, acc);
  #pragma unroll
  for (int ct=0;ct<8;ct++)
    #pragma unroll
    for (int i=0;i<4;i++){
      int r = wid*16 + lg*4 + i, c = ct*16 + l15;
      sVh[r*130 + c] = f2bf(acc[ct][i]);
    }
  __syncthreads();
  {
    int bb = rowbase >> 11;
    int n0 = rowbase & 2047;
    #pragma unroll
    for (int it=0; it<4; ++it){
      int idx = tid + it*256;
      int f = idx >> 3, ch = idx & 7;
      bf16x8 pk;
      #pragma unroll
      for (int j=0;j<8;j++) pk[j] = (short)sVh[(ch*8+j)*130 + f];
      int ci = (n0 >> 3) + ch;
      *reinterpret_cast<bf16x8*>(vht + bb*(DIM*SEQ) + f*SEQ + ci*8) = pk;
    }
  }
}

// ---------------- kernel 2: flash attention, split-KV x2, adj fused (reg-staged, non-temporal) ----------------
__global__ __launch_bounds__(256,2) void attn(const unsigned short* __restrict__ qh,
                                              const unsigned short* __restrict__ khsw,
                                              const unsigned short* __restrict__ vht,
                                              const float* __restrict__ adj,
                                              unsigned short* __restrict__ po,
                                              float* __restrict__ pml){
  __shared__ unsigned short sK[2][64*128];
  __shared__ unsigned short sV[2][128*64];
  __shared__ unsigned short sP[4][16*72];

  const int tid = threadIdx.x;
  const int lane = tid & 63, wid = tid >> 6;
  const int l15 = lane & 15, lg = lane >> 4;
  const int bfid = blockIdx.x;
  const int half = bfid >> 8;
  const int rest = bfid & 255;
  const int b = rest & 7, qblk = rest >> 3;     // bfid%8 == b for both halves -> same XCD
  const int qbase = qblk * 64;
  const int tokbase = b*SEQ + qbase;
  const int kvbase = half * 1024;
  const unsigned short* vhb = vht + (size_t)b*DIM*SEQ;
  // lane's adj base: rows (qbase + wid*16 + lg*4 + i), col (kvbase + ct*16 + l15)
  const float* adjl = adj + ((size_t)b*SEQ + qbase + wid*16 + lg*4)*SEQ + kvbase + l15;

  bf16x8 qf[4];
  {
    const unsigned short* qp = qh + (size_t)(tokbase + wid*16 + l15)*128;
    #pragma unroll
    for (int kt=0;kt<4;kt++) qf[kt] = *reinterpret_cast<const bf16x8*>(qp + kt*32 + lg*8);
  }

  f32x4 o[8];
  #pragma unroll
  for (int ct=0;ct<8;ct++) o[ct] = (f32x4){0.f,0.f,0.f,0.f};
  float mrow[4], lrow[4];
  #pragma unroll
  for (int i=0;i<4;i++){ mrow[i] = -3e38f; lrow[i] = 0.f; }

  auto stage = [&](int tt, int db){
    const char* kbase = (const char*)(khsw + (size_t)(b*SEQ + kvbase + tt*64)*128);
    #pragma unroll
    for (int p=0;p<4;p++)
      gld16(kbase + p*4096 + tid*16, (const char*)sK[db] + p*4096 + wid*1024);
    #pragma unroll
    for (int p=0;p<4;p++){
      int u = p*256 + tid;
      int ff = u >> 3, cp = u & 7;
      gld16(vhb + (size_t)ff*SEQ + kvbase + tt*64 + ((cp ^ (ff&7))*8),
            (const char*)sV[db] + p*4096 + wid*1024);
    }
  };

  auto ldadj = [&](int tt, float a[16]){
    const float* ap = adjl + tt*64;
    #pragma unroll
    for (int i=0;i<4;i++)
      #pragma unroll
      for (int ct=0;ct<4;ct++)
        a[i*4+ct] = __builtin_nontemporal_load(ap + (size_t)i*SEQ + ct*16);
  };

  auto body = [&](int t, int db, const float a[16]){
    const unsigned short* K = sK[db];
    const unsigned short* V = sV[db];

    // S = Q K^T
    f32x4 s[4];
    #pragma unroll
    for (int ct=0;ct<4;ct++) s[ct] = (f32x4){0.f,0.f,0.f,0.f};
    #pragma unroll
    for (int kt=0;kt<4;kt++){
      #pragma unroll
      for (int ct=0;ct<4;ct++){
        int kr = ct*16 + l15;
        bf16x8 kf = *reinterpret_cast<const bf16x8*>(K + kr*128 + (((kt*4+lg) ^ (kr&7))*8));
        s[ct] = __builtin_amdgcn_mfma_f32_16x16x32_bf16(qf[kt], kf, s[ct], 0,0,0);
      }
    }

    // mask from registers
    #pragma unroll
    for (int i=0;i<4;i++)
      #pragma unroll
      for (int ct=0;ct<4;ct++)
        if (a[i*4+ct] == 0.f) s[ct][i] = -1e9f;

    // online softmax (exp2 domain), defer-max THR=8
    #pragma unroll
    for (int i=0;i<4;i++){
      float pm = fmaxf(fmaxf(s[0][i], s[1][i]), fmaxf(s[2][i], s[3][i]));
      pm = rmax16(pm);
      if (__any(pm > mrow[i] + 8.f)){
        float nm = fmaxf(mrow[i], pm);
        float scv = exp2f(mrow[i] - nm);
        mrow[i] = nm;
        lrow[i] *= scv;
        #pragma unroll
        for (int ct=0;ct<8;ct++) o[ct][i] *= scv;
      }
      float p0 = exp2f(s[0][i] - mrow[i]);
      float p1 = exp2f(s[1][i] - mrow[i]);
      float p2 = exp2f(s[2][i] - mrow[i]);
      float p3 = exp2f(s[3][i] - mrow[i]);
      s[0][i]=p0; s[1][i]=p1; s[2][i]=p2; s[3][i]=p3;
      lrow[i] += rsum16(p0+p1+p2+p3);
    }

    // P -> per-wave LDS (C-layout -> A-layout)
    unsigned short* Pw = sP[wid];
    #pragma unroll
    for (int ct=0;ct<4;ct++)
      #pragma unroll
      for (int i=0;i<4;i++)
        Pw[(lg*4+i)*72 + ct*16 + l15] = f2bf(s[ct][i]);
    bf16x8 pa[2];
    #pragma unroll
    for (int sl=0;sl<2;sl++)
      pa[sl] = *reinterpret_cast<const bf16x8*>(Pw + l15*72 + sl*32 + lg*8);

    // O += P V
    #pragma unroll
    for (int ct=0;ct<8;ct++){
      int ff = ct*16 + l15;
      bf16x8 v0 = *reinterpret_cast<const bf16x8*>(V + ff*64 + ((lg ^ (ff&7))*8));
      bf16x8 v1 = *reinterpret_cast<const bf16x8*>(V + ff*64 + (((4+lg) ^ (ff&7))*8));
      o[ct] = __builtin_amdgcn_mfma_f32_16x16x32_bf16(pa[0], v0, o[ct], 0,0,0);
      o[ct] = __builtin_amdgcn_mfma_f32_16x16x32_bf16(pa[1], v1, o[ct], 0,0,0);
    }
    __syncthreads();
  };

  float afA[16], afB[16];
  ldadj(0, afA);
  stage(0, 0);
  __syncthreads();

  #pragma unroll 1
  for (int t=0; t<16; t+=2){
    if (t+1 < 16){ stage(t+1, 1); ldadj(t+1, afB); }
    body(t, 0, afA);
    if (t+2 < 16){ stage(t+2, 0); ldadj(t+2, afA); }
    if (t+1 < 16) body(t+1, 1, afB);
  }

  // write unnormalized partials + (m,l)
  #pragma unroll
  for (int ct=0;ct<8;ct++)
    #pragma unroll
    for (int i=0;i<4;i++){
      int row = tokbase + wid*16 + lg*4 + i;
      po[(size_t)(half*TOK + row)*128 + ct*16 + l15] = f2bf(o[ct][i]);
    }
  if (l15 == 0){
    #pragma unroll
    for (int i=0;i<4;i++){
      int row = tokbase + wid*16 + lg*4 + i;
      pml[(size_t)row*4 + half*2 + 0] = mrow[i];
      pml[(size_t)row*4 + half*2 + 1] = lrow[i];
    }
  }
}

// ---------------- kernel 3: merge split-KV partials ----------------
__global__ __launch_bounds__(256) void merge(const unsigned short* __restrict__ po,
                                             const float* __restrict__ pml,
                                             float* __restrict__ out){
  const int mblk = blockIdx.x;
  const int b = mblk & 7, qblk = mblk >> 3;     // same XCD as producers
  const int tokbase = b*SEQ + qblk*64;
  const int tid = threadIdx.x;
  const int row = tokbase + (tid >> 2);
  const int c0 = (tid & 3) * 32;

  f32x4 ml = *reinterpret_cast<const f32x4*>(pml + (size_t)row*4);
  float M = fmaxf(ml[0], ml[2]);
  float a0 = exp2f(ml[0] - M), a1 = exp2f(ml[2] - M);
  float inv = 1.f / (ml[1]*a0 + ml[3]*a1);
  a0 *= inv; a1 *= inv;

  const unsigned short* p0 = po + (size_t)row*128 + c0;
  const unsigned short* p1 = po + (size_t)(TOK + row)*128 + c0;
  float* op = out + (size_t)row*256 + c0;
  #pragma unroll
  for (int k=0;k<4;k++){
    bf16x8 v0 = *reinterpret_cast<const bf16x8*>(p0 + k*8);
    bf16x8 v1 = *reinterpret_cast<const bf16x8*>(p1 + k*8);
    float4 r0, r1;
    r0.x = bf2f((unsigned short)v0[0])*a0 + bf2f((unsigned short)v1[0])*a1;
    r0.y = bf2f((unsigned short)v0[1])*a0 + bf2f((unsigned short)v1[1])*a1;
    r0.z = bf2f((unsigned short)v0[2])*a0 + bf2f((unsigned short)v1[2])*a1;
    r0.w = bf2f((unsigned short)v0[3])*a0 + bf2f((unsigned short)v1[3])*a1;
    r1.x = bf2f((unsigned short)v0[4])*a0 + bf2f((unsigned short)v1[4])*a1;
    r1.y = bf2f((unsigned short)v0[5])*a0 + bf2f((unsigned short)v1[5])*a1;
    r1.z = bf2f((unsigned short)v0[6])*a0 + bf2f((unsigned short)v1[6])*a1;
    r1.w = bf2f((unsigned short)v0[7])*a0 + bf2f((unsigned short)v1[7])*a1;
    *reinterpret_cast<float4*>(op + k*8)     = r0;
    *reinterpret_cast<float4*>(op + k*8 + 4) = r1;
  }
}

extern "C" void kernel_launch(void* const* d_in, const int* in_sizes, int n_in,
                              void* d_out, int out_size, void* d_ws, size_t ws_size,
                              hipStream_t stream){
  (void)in_sizes; (void)n_in; (void)out_size; (void)ws_size;
  const float* q   = (const float*)d_in[0];
  const float* adj = (const float*)d_in[3];
  const float* W1  = (const float*)d_in[4];
  const float* Wq  = (const float*)d_in[5];
  const float* Wk  = (const float*)d_in[6];
  const float* Wv  = (const float*)d_in[7];
  float* out = (float*)d_out;

  unsigned short* qh = (unsigned short*)d_ws;        // 4 MB
  unsigned short* kh = qh + (size_t)TOK*DIM;         // 4 MB
  unsigned short* vh = kh + (size_t)TOK*DIM;         // 4 MB
  unsigned short* wt = vh + (size_t)TOK*DIM;         // 128 KB
  unsigned short* po = wt + 4*128*128;               // 8 MB (2 x bf16 partial O)
  float*          pml = (float*)(po + (size_t)2*TOK*DIM);  // 256 KB

  prep_w<<<16,  256, 0, stream>>>(W1, Wq, Wk, Wv, wt);
  proj  <<<256, 256, 0, stream>>>(q, wt, out, qh, kh, vh);
  attn  <<<512, 256, 0, stream>>>(qh, kh, vh, adj, po, pml);
  merge <<<256, 256, 0, stream>>>(po, pml, out);
}